// Round 11
// baseline (4067.475 us; speedup 1.0000x reference)
//
#include <hip/hip_runtime.h>
#include <cstdint>
#include <cstddef>

#define DEVI __device__ __forceinline__

typedef __attribute__((ext_vector_type(8))) short bf16x8;
typedef __attribute__((ext_vector_type(4))) float f32x4;
typedef unsigned short ushort_t;
typedef unsigned int uint_t;

// problem dims (fixed)
constexpr int NB = 64;    // batch
constexpr int NTT = 512;  // seq len
constexpr int NI = 512;   // input feat
constexpr int NH = 1024;  // hidden
constexpr int NA = 512;   // out feat
constexpr int NG = 4096;  // 4*NH
constexpr int CHUNK = 64; // scan chunk (timesteps per launch)

DEVI float bf2f(ushort_t u) { union { uint_t i; float f; } v; v.i = ((uint_t)u) << 16; return v.f; }
DEVI ushort_t f2bf(float f) {
  union { float f; uint_t i; } v; v.f = f;
  uint_t x = v.i;
  return (ushort_t)((x + 0x7fffu + ((x >> 16) & 1u)) >> 16);
}

// clamped fast tanh: safe for |x| large (clamp before exp), bf16-accurate
DEVI float tanh_f(float x) {
  x = fminf(fmaxf(x, -15.f), 15.f);
  float e = __expf(2.f * x);
  return (e - 1.f) / (e + 1.f);
}

DEVI void gload_lds16(const void* g, void* l) {
  __builtin_amdgcn_global_load_lds((__attribute__((address_space(1))) void*)g,
                                   (__attribute__((address_space(3))) void*)l, 16, 0, 0);
}

// ---------------- cast fp32 -> bf16 ----------------
__global__ __launch_bounds__(256) void cast_f32_bf16(const float* __restrict__ in,
                                                     ushort_t* __restrict__ out, int n) {
  int i = (blockIdx.x * 256 + threadIdx.x) * 4;
  if (i >= n) return;
  float4 v = *(const float4*)(in + i);
  ushort4 o;
  o.x = f2bf(v.x); o.y = f2bf(v.y); o.z = f2bf(v.z); o.w = f2bf(v.w);
  *(ushort4*)(out + i) = o;
}

// ---------------- generic NT GEMM: C[M,N] = A[M,K] * B[N,K]^T ----------------
// MODE 0: fp32 out, +bias0 (fc3) | MODE 1: bf16 out, tanh (fc1) |
// MODE 2: chunked gx, scatter to gxc[tl][wg][b][g*16+u]
template <int MODE>
__global__ __launch_bounds__(256) void gemm_nt(const short* __restrict__ A,
                                               const short* __restrict__ Bm,
                                               const float* __restrict__ bias0,
                                               const float* __restrict__ bias1,
                                               void* __restrict__ Cout,
                                               int M, int N, int K, int t0) {
  __shared__ short As[128 * 32];
  __shared__ short Bs[128 * 32];
  const int tid = threadIdx.x;
  const int wave = tid >> 6, lane = tid & 63;
  const int m0 = blockIdx.y * 128, n0 = blockIdx.x * 128;
  const int wr = wave >> 1, wc = wave & 1;

  f32x4 zero = {0.f, 0.f, 0.f, 0.f};
  f32x4 acc[4][4];
#pragma unroll
  for (int i = 0; i < 4; ++i)
#pragma unroll
    for (int j = 0; j < 4; ++j) acc[i][j] = zero;

  const int lrow = lane >> 2;
  const int lk = (lane & 3) * 8;

  for (int kt = 0; kt < K; kt += 32) {
#pragma unroll
    for (int c = 0; c < 2; ++c) {
      int q = wave + 4 * c;
      int row = m0 + q * 16 + lrow;
      long arow = (MODE == 2) ? ((long)(row >> 6) * NTT + t0 + (row & 63)) : (long)row;
      gload_lds16(A + arow * K + kt + lk, As + q * 512);
      gload_lds16(Bm + (long)(n0 + q * 16 + lrow) * K + kt + lk, Bs + q * 512);
    }
    __syncthreads();

    bf16x8 av[4], bv[4];
#pragma unroll
    for (int i = 0; i < 4; ++i) {
      int row = wr * 64 + i * 16 + (lane & 15);
      av[i] = *(const bf16x8*)(As + row * 32 + (lane >> 4) * 8);
    }
#pragma unroll
    for (int j = 0; j < 4; ++j) {
      int col = wc * 64 + j * 16 + (lane & 15);
      bv[j] = *(const bf16x8*)(Bs + col * 32 + (lane >> 4) * 8);
    }
#pragma unroll
    for (int i = 0; i < 4; ++i)
#pragma unroll
      for (int j = 0; j < 4; ++j)
        acc[i][j] = __builtin_amdgcn_mfma_f32_16x16x32_bf16(av[i], bv[j], acc[i][j], 0, 0, 0);
    __syncthreads();
  }

  const int fq = lane >> 4, fr = lane & 15;
#pragma unroll
  for (int i = 0; i < 4; ++i) {
#pragma unroll
    for (int j = 0; j < 4; ++j) {
      int gcol = n0 + wc * 64 + j * 16 + fr;
      float bsum = bias0[gcol];
      if (MODE == 2) bsum += bias1[gcol];
#pragma unroll
      for (int r = 0; r < 4; ++r) {
        int gm = m0 + wr * 64 + i * 16 + fq * 4 + r;
        float v = acc[i][j][r] + bsum;
        if (MODE == 0) {
          ((float*)Cout)[(long)gm * N + gcol] = v;
        } else if (MODE == 1) {
          ((ushort_t*)Cout)[(long)gm * N + gcol] = f2bf(tanhf(v));
        } else {
          int b = gm >> 6, tl = gm & 63;
          int wgp = (gcol >> 4) & 63, g = gcol >> 10, u = gcol & 15;
          ((ushort_t*)Cout)[((((long)tl * 64 + wgp) * 64 + b) << 6) + g * 16 + u] = f2bf(v);
        }
      }
    }
  }
}

// ---------------- persistent LSTM scan (one chunk of CHUNK timesteps) ----------------
// 64 WGs x 512 threads; WG owns 16 hidden units. Waves: g = K-half, w2 = batch group.
// R11 role split (kill vmcnt self-interference on the barrier):
//   waves 0-3 (g0): h-load, MFMA, gates, h agent-stores; hs stores AFTER flag.
//   waves 4-5: gx slice -> LDS via global_load_lds (issued post-release, overlaps poll).
//   wave 7:   dedicated poller — nothing else on its vmcnt -> clean detect.
// Flags at 128B stride (best measured). Weights fragment-ordered in LDS (conflict-free).
__global__ __launch_bounds__(512, 2) void lstm_scan(const ushort_t* __restrict__ whh,
                                                    const ushort_t* __restrict__ gxc,  // [CHUNK][64][NB][64]
                                                    ushort_t* __restrict__ hseq,       // [CHUNK+1][NB][NH]
                                                    float* __restrict__ cbuf,          // [NB][NH]
                                                    ushort_t* __restrict__ hs,         // [NB][NTT][NH]
                                                    uint_t* __restrict__ flags,        // 128B stride
                                                    int t0, uint_t tbase) {
  extern __shared__ char smem[];
  float* pre = (float*)(smem + 64 * NH * 2);                    // [64][65] fp32
  ushort_t* gxl = (ushort_t*)(smem + 64 * NH * 2 + 64 * 65 * 4);  // [64][64] bf16 (8KB)
  const int wg = blockIdx.x, tid = threadIdx.x;
  const int wave = tid >> 6, lane = tid & 63;
  const int fq = lane >> 4, fr = lane & 15;
  const int g = wave >> 2, w2 = wave & 3;

  // stage weights into fragment-ordered LDS:
  // frag[(ksg*4+nt)*64 + fq*16 + fr] <- W[n=nt*16+fr][k=ksg*32+fq*8 ..+8]
  for (int idx = tid; idx < 64 * 128; idx += 512) {
    int n = idx >> 7, kc = idx & 127;
    int grow = (n >> 4) * NH + wg * 16 + (n & 15);
    bf16x8 w = *(const bf16x8*)(whh + (long)grow * NH + kc * 8);
    int frag = ((kc >> 2) * 4 + (n >> 4)) * 64 + (kc & 3) * 16 + (n & 15);
    *(bf16x8*)(smem + frag * 16) = w;
  }
  const int bb = w2 * 16;          // batch base for this wave
  const int abrow = bb + fr;       // A-frag row (batch)
  const int lane16 = lane * 16;
  f32x4 zero = {0.f, 0.f, 0.f, 0.f};

  // h(t=-1)=0 init
  if (t0 == 0) {
    int cb = tid >> 3, cup = tid & 7;
    uint_t* p = (uint_t*)(hseq + cb * NH + wg * 16 + cup * 2);
    __hip_atomic_store(p, 0u, __ATOMIC_RELAXED, __HIP_MEMORY_SCOPE_AGENT);
  }
  // c-state: g0 lanes own (b=bb+4fq+r, u=fr)
  float cc[4];
  if (g == 0) {
#pragma unroll
    for (int r = 0; r < 4; ++r)
      cc[r] = (t0 == 0) ? 0.f : cbuf[(bb + fq * 4 + r) * NH + wg * 16 + fr];
  }

  auto stage_gx = [&](int tl) {  // waves 4,5: contiguous 8KB slice -> LDS
    if (wave == 4 || wave == 5) {
      const ushort_t* src = gxc + ((size_t)tl * 64 + wg) * 4096;
#pragma unroll
      for (int i = 0; i < 4; ++i) {
        int c = (wave - 4) * 4 + i;  // 1KB chunk id
        gload_lds16(src + c * 512 + lane * 8, gxl + c * 512);
      }
    }
  };
  auto poll = [&](uint_t t) {  // wave 7: dedicated poller
    if (wave == 7) {
      uint_t* fp = flags + lane * 32;
      for (;;) {
        uint_t v = __hip_atomic_load(fp, __ATOMIC_RELAXED, __HIP_MEMORY_SCOPE_AGENT);
        if (__all(v >= t)) break;
        __builtin_amdgcn_s_sleep(1);
      }
    }
  };

  // initial barrier: weights staged, h slot0 + c ready; stage gx(0) during poll
  asm volatile("s_waitcnt vmcnt(0)" ::: "memory");
  __syncthreads();
  if (tid == 0)
    __hip_atomic_store(flags + wg * 32, tbase + 1, __ATOMIC_RELAXED, __HIP_MEMORY_SCOPE_AGENT);
  stage_gx(0);
  poll(tbase + 1);
  __syncthreads();
  __builtin_amdgcn_fence(__ATOMIC_ACQUIRE, "agent");  // drop stale hseq lines (belt&braces)
  __syncthreads();

  for (int tl = 0; tl < CHUNK; ++tl) {
    const ushort_t* hc = hseq + (size_t)tl * (NB * NH);
    // bulk-stage this wave's disjoint K-half slice: 16 x 16B loads in flight
    bf16x8 areg[16];
#pragma unroll
    for (int ks = 0; ks < 16; ++ks) {
      int ksg = g * 16 + ((ks + wg) & 15);  // per-WG rotation de-bursts LLC lines
      areg[ks] = *(const bf16x8*)(hc + abrow * NH + ksg * 32 + fq * 8);
    }
    __builtin_amdgcn_sched_barrier(0);

    f32x4 acc[4] = {zero, zero, zero, zero};
#pragma unroll
    for (int ks = 0; ks < 16; ++ks) {
      int ksg = g * 16 + ((ks + wg) & 15);
#pragma unroll
      for (int nt = 0; nt < 4; ++nt) {
        bf16x8 w = *(const bf16x8*)(smem + ((ksg * 4 + nt) << 10) + lane16);
        acc[nt] = __builtin_amdgcn_mfma_f32_16x16x32_bf16(areg[ks], w, acc[nt], 0, 0, 0);
      }
    }
    // g1 dumps K-half partials
    if (g == 1) {
#pragma unroll
      for (int nt = 0; nt < 4; ++nt)
#pragma unroll
        for (int r = 0; r < 4; ++r)
          pre[(bb + fq * 4 + r) * 65 + nt * 16 + fr] = acc[nt][r];
    }
    if (wave == 4 || wave == 5)  // gx staging (issued last step) complete before gates read it
      asm volatile("s_waitcnt vmcnt(0)" ::: "memory");
    __syncthreads();  // S1: pre + gxl(t) ready

    // g0: combine + gates in-register (gate = nt, unit = fr, batch = bb+4fq+r)
    uint_t hp[4];
    if (g == 0) {
#pragma unroll
      for (int r = 0; r < 4; ++r) {
        int b = bb + fq * 4 + r;
        float xi = pre[b * 65 + fr] + acc[0][r] + bf2f(gxl[b * 64 + fr]);
        float xf = pre[b * 65 + 16 + fr] + acc[1][r] + bf2f(gxl[b * 64 + 16 + fr]);
        float xg = pre[b * 65 + 32 + fr] + acc[2][r] + bf2f(gxl[b * 64 + 32 + fr]);
        float xo = pre[b * 65 + 48 + fr] + acc[3][r] + bf2f(gxl[b * 64 + 48 + fr]);
        float ig = 1.f / (1.f + __expf(-xi));
        float fg = 1.f / (1.f + __expf(-xf));
        float gg = tanh_f(xg);
        float og = 1.f / (1.f + __expf(-xo));
        cc[r] = fg * cc[r] + ig * gg;
        float hv = og * tanh_f(cc[r]);
        uint_t hb = (uint_t)f2bf(hv);
        uint_t other = (uint_t)__shfl_xor((int)hb, 1, 64);  // pair units fr<->fr^1
        hp[r] = hb | (other << 16);                          // valid on even fr
        if (!(fr & 1)) {
          uint_t* hdst = (uint_t*)(hseq + (size_t)(tl + 1) * (NB * NH) + b * NH + wg * 16 + fr);
          __hip_atomic_store(hdst, hp[r], __ATOMIC_RELAXED, __HIP_MEMORY_SCOPE_AGENT);
          if (tl == CHUNK - 1) {  // hand h(final) to next chunk's slot 0
            uint_t* h0 = (uint_t*)(hseq + b * NH + wg * 16 + fr);
            __hip_atomic_store(h0, hp[r], __ATOMIC_RELAXED, __HIP_MEMORY_SCOPE_AGENT);
          }
        }
      }
    }

    // ---- release: drain h stores only, then flag ----
    asm volatile("s_waitcnt vmcnt(0)" ::: "memory");  // g0 h-stores acked at LLC
    __syncthreads();                                  // S2
    uint_t t = tbase + 2 + tl;
    if (tid == 0)
      __hip_atomic_store(flags + wg * 32, t, __ATOMIC_RELAXED, __HIP_MEMORY_SCOPE_AGENT);
    // off-critical-path, AFTER the flag: hs stores (g0) + gx staging (w4-5)
    if (g == 0 && !(fr & 1)) {
#pragma unroll
      for (int r = 0; r < 4; ++r)
        *(uint_t*)(hs + ((size_t)(bb + fq * 4 + r) * NTT + t0 + tl) * NH + wg * 16 + fr) = hp[r];
    }
    if (tl + 1 < CHUNK) stage_gx(tl + 1);
    poll(t);  // wave 7 only: clean vmcnt -> fast detect
    __syncthreads();  // S3
    asm volatile("" ::: "memory");
  }
  // persist c for next chunk
  if (g == 0) {
#pragma unroll
    for (int r = 0; r < 4; ++r)
      cbuf[(bb + fq * 4 + r) * NH + wg * 16 + fr] = cc[r];
  }
}

// ---------------- host ----------------
extern "C" void kernel_launch(void* const* d_in, const int* in_sizes, int n_in,
                              void* d_out, int out_size, void* d_ws, size_t ws_size,
                              hipStream_t stream) {
  const float* x = (const float*)d_in[0];
  const float* w1 = (const float*)d_in[1];
  const float* b1 = (const float*)d_in[2];
  const float* w_ih = (const float*)d_in[3];
  const float* w_hh = (const float*)d_in[4];
  const float* b_ih = (const float*)d_in[5];
  const float* b_hh = (const float*)d_in[6];
  const float* w3 = (const float*)d_in[7];
  const float* b3 = (const float*)d_in[8];

  char* ws = (char*)d_ws;
  size_t off = 0;
  auto alloc = [&](size_t bytes) {
    char* p = ws + off;
    off += (bytes + 255) & ~(size_t)255;
    return p;
  };
  ushort_t* w1b = (ushort_t*)alloc(sizeof(ushort_t) * NH * NI);
  ushort_t* wihb = (ushort_t*)alloc(sizeof(ushort_t) * NG * NH);
  ushort_t* whhb = (ushort_t*)alloc(sizeof(ushort_t) * NG * NH);
  ushort_t* w3b = (ushort_t*)alloc(sizeof(ushort_t) * NA * NH);
  ushort_t* fb = (ushort_t*)alloc(sizeof(ushort_t) * (size_t)NB * NTT * NH);  // f, then hs (in-place)
  float* cbuf = (float*)alloc(sizeof(float) * NB * NH);
  uint_t* flags = (uint_t*)alloc(sizeof(uint_t) * 64 * 32);
  if (off > ws_size) {
    hipMemsetAsync(d_out, 0xFF, 256, stream);  // NaN sentinel: ws too small
    return;
  }

  // scratch carved out of d_out (dead before fc3 writes d_out):
  ushort_t* xb = (ushort_t*)d_out;                           // bf16 x for fc1
  ushort_t* hseq = (ushort_t*)d_out;                         // [CHUNK+1][NB][NH] (reuses xb)
  ushort_t* gxc = (ushort_t*)d_out + (size_t)NB * NTT * NI;  // [CHUNK][64][NB][64]

  auto cast = [&](const float* src, ushort_t* dst, int n) {
    cast_f32_bf16<<<dim3((n / 4 + 255) / 256), dim3(256), 0, stream>>>(src, dst, n);
  };
  cast(x, xb, NB * NTT * NI);
  cast(w1, w1b, NH * NI);
  cast(w_ih, wihb, NG * NH);
  cast(w_hh, whhb, NG * NH);
  cast(w3, w3b, NA * NH);

  // fc1 + tanh -> f (bf16)
  gemm_nt<1><<<dim3(NH / 128, NB * NTT / 128), dim3(256), 0, stream>>>(
      (const short*)xb, (const short*)w1b, b1, nullptr, fb, NB * NTT, NH, NI, 0);

  hipMemsetAsync(flags, 0, sizeof(uint_t) * 64 * 32, stream);
  int ldsz = 64 * NH * 2 + 64 * 65 * 4 + 64 * 64 * 2;
  hipFuncSetAttribute(reinterpret_cast<const void*>(&lstm_scan),
                      hipFuncAttributeMaxDynamicSharedMemorySize, ldsz);

  for (int chunk = 0; chunk < NTT / CHUNK; ++chunk) {
    int t0 = chunk * CHUNK;
    gemm_nt<2><<<dim3(NG / 128, NB * CHUNK / 128), dim3(256), 0, stream>>>(
        (const short*)fb, (const short*)wihb, b_ih, b_hh, gxc, NB * CHUNK, NG, NH, t0);
    lstm_scan<<<dim3(64), dim3(512), ldsz, stream>>>(
        whhb, gxc, hseq, cbuf, fb, flags, t0, (uint_t)(chunk * (CHUNK + 1)));
  }

  // fc3 head -> d_out (fp32)
  gemm_nt<0><<<dim3(NA / 128, NB * NTT / 128), dim3(256), 0, stream>>>(
      (const short*)fb, (const short*)w3b, b3, nullptr, d_out, NB * NTT, NA, NH, 0);
}

// Round 12
// 4007.309 us; speedup vs baseline: 1.0150x; 1.0150x over previous
//
#include <hip/hip_runtime.h>
#include <cstdint>
#include <cstddef>

#define DEVI __device__ __forceinline__

typedef __attribute__((ext_vector_type(8))) short bf16x8;
typedef __attribute__((ext_vector_type(4))) float f32x4;
typedef unsigned short ushort_t;
typedef unsigned int uint_t;

// problem dims (fixed)
constexpr int NB = 64;    // batch
constexpr int NTT = 512;  // seq len
constexpr int NI = 512;   // input feat
constexpr int NH = 1024;  // hidden
constexpr int NA = 512;   // out feat
constexpr int NG = 4096;  // 4*NH
constexpr int CHUNK = 64; // scan chunk (timesteps per launch)

DEVI float bf2f(ushort_t u) { union { uint_t i; float f; } v; v.i = ((uint_t)u) << 16; return v.f; }
DEVI ushort_t f2bf(float f) {
  union { float f; uint_t i; } v; v.f = f;
  uint_t x = v.i;
  return (ushort_t)((x + 0x7fffu + ((x >> 16) & 1u)) >> 16);
}

// clamped fast tanh: safe for |x| large (clamp before exp), bf16-accurate
DEVI float tanh_f(float x) {
  x = fminf(fmaxf(x, -15.f), 15.f);
  float e = __expf(2.f * x);
  return (e - 1.f) / (e + 1.f);
}

DEVI void gload_lds16(const void* g, void* l) {
  __builtin_amdgcn_global_load_lds((__attribute__((address_space(1))) void*)g,
                                   (__attribute__((address_space(3))) void*)l, 16, 0, 0);
}

// ---------------- cast fp32 -> bf16 ----------------
__global__ __launch_bounds__(256) void cast_f32_bf16(const float* __restrict__ in,
                                                     ushort_t* __restrict__ out, int n) {
  int i = (blockIdx.x * 256 + threadIdx.x) * 4;
  if (i >= n) return;
  float4 v = *(const float4*)(in + i);
  ushort4 o;
  o.x = f2bf(v.x); o.y = f2bf(v.y); o.z = f2bf(v.z); o.w = f2bf(v.w);
  *(ushort4*)(out + i) = o;
}

// ---------------- generic NT GEMM: C[M,N] = A[M,K] * B[N,K]^T ----------------
// MODE 0: fp32 out, +bias0 (fc3) | MODE 1: bf16 out, tanh (fc1) |
// MODE 2: chunked gx, scatter to gxc[tl][wg][b][g*16+u]
template <int MODE>
__global__ __launch_bounds__(256) void gemm_nt(const short* __restrict__ A,
                                               const short* __restrict__ Bm,
                                               const float* __restrict__ bias0,
                                               const float* __restrict__ bias1,
                                               void* __restrict__ Cout,
                                               int M, int N, int K, int t0) {
  __shared__ short As[128 * 32];
  __shared__ short Bs[128 * 32];
  const int tid = threadIdx.x;
  const int wave = tid >> 6, lane = tid & 63;
  const int m0 = blockIdx.y * 128, n0 = blockIdx.x * 128;
  const int wr = wave >> 1, wc = wave & 1;

  f32x4 zero = {0.f, 0.f, 0.f, 0.f};
  f32x4 acc[4][4];
#pragma unroll
  for (int i = 0; i < 4; ++i)
#pragma unroll
    for (int j = 0; j < 4; ++j) acc[i][j] = zero;

  const int lrow = lane >> 2;
  const int lk = (lane & 3) * 8;

  for (int kt = 0; kt < K; kt += 32) {
#pragma unroll
    for (int c = 0; c < 2; ++c) {
      int q = wave + 4 * c;
      int row = m0 + q * 16 + lrow;
      long arow = (MODE == 2) ? ((long)(row >> 6) * NTT + t0 + (row & 63)) : (long)row;
      gload_lds16(A + arow * K + kt + lk, As + q * 512);
      gload_lds16(Bm + (long)(n0 + q * 16 + lrow) * K + kt + lk, Bs + q * 512);
    }
    __syncthreads();

    bf16x8 av[4], bv[4];
#pragma unroll
    for (int i = 0; i < 4; ++i) {
      int row = wr * 64 + i * 16 + (lane & 15);
      av[i] = *(const bf16x8*)(As + row * 32 + (lane >> 4) * 8);
    }
#pragma unroll
    for (int j = 0; j < 4; ++j) {
      int col = wc * 64 + j * 16 + (lane & 15);
      bv[j] = *(const bf16x8*)(Bs + col * 32 + (lane >> 4) * 8);
    }
#pragma unroll
    for (int i = 0; i < 4; ++i)
#pragma unroll
      for (int j = 0; j < 4; ++j)
        acc[i][j] = __builtin_amdgcn_mfma_f32_16x16x32_bf16(av[i], bv[j], acc[i][j], 0, 0, 0);
    __syncthreads();
  }

  const int fq = lane >> 4, fr = lane & 15;
#pragma unroll
  for (int i = 0; i < 4; ++i) {
#pragma unroll
    for (int j = 0; j < 4; ++j) {
      int gcol = n0 + wc * 64 + j * 16 + fr;
      float bsum = bias0[gcol];
      if (MODE == 2) bsum += bias1[gcol];
#pragma unroll
      for (int r = 0; r < 4; ++r) {
        int gm = m0 + wr * 64 + i * 16 + fq * 4 + r;
        float v = acc[i][j][r] + bsum;
        if (MODE == 0) {
          ((float*)Cout)[(long)gm * N + gcol] = v;
        } else if (MODE == 1) {
          ((ushort_t*)Cout)[(long)gm * N + gcol] = f2bf(tanhf(v));
        } else {
          int b = gm >> 6, tl = gm & 63;
          int wgp = (gcol >> 4) & 63, g = gcol >> 10, u = gcol & 15;
          ((ushort_t*)Cout)[((((long)tl * 64 + wgp) * 64 + b) << 6) + g * 16 + u] = f2bf(v);
        }
      }
    }
  }
}

// ---------------- persistent LSTM scan: 4 independent batch-group pipelines ----------------
// 64 WGs x 256 threads (4 waves). Wave gid owns batch group gid (16 batches),
// FULL K=1024 -> no partial combine, no __syncthreads in the steady loop.
// Each group has its own hseq[CHUNK+1][16][NH], flags row, c-state; its 64-WG
// barrier runs out of phase with the other groups (separate SIMDs hide waits).
// LDS: weights only (128 KB, fragment-ordered, conflict-free, read-only).
__global__ __launch_bounds__(256, 1) void lstm_scan(const ushort_t* __restrict__ whh,
                                                    const ushort_t* __restrict__ gxc,   // [CHUNK][64][NB][64]
                                                    ushort_t* __restrict__ hseq,        // [4][CHUNK+1][16][NH]
                                                    float* __restrict__ cbuf,           // [NB][NH]
                                                    ushort_t* __restrict__ hs,          // [NB][NTT][NH]
                                                    uint_t* __restrict__ flags,         // [4][64*32]
                                                    int t0, uint_t tbase) {
  extern __shared__ char smem[];  // 128 KB fragment-ordered weights
  const int wg = blockIdx.x, tid = threadIdx.x;
  const int gid = tid >> 6, lane = tid & 63;   // wave == batch group
  const int fq = lane >> 4, fr = lane & 15;
  const int lane16 = lane * 16;
  f32x4 zero = {0.f, 0.f, 0.f, 0.f};

  // stage weights into fragment-ordered LDS:
  // frag[(ksg*4+nt)*64 + fq*16 + fr] <- W[n=nt*16+fr][k=ksg*32+fq*8 ..+8]
  for (int idx = tid; idx < 64 * 128; idx += 256) {
    int n = idx >> 7, kc = idx & 127;
    int grow = (n >> 4) * NH + wg * 16 + (n & 15);
    bf16x8 w = *(const bf16x8*)(whh + (long)grow * NH + kc * 8);
    int frag = ((kc >> 2) * 4 + (n >> 4)) * 64 + (kc & 3) * 16 + (n & 15);
    *(bf16x8*)(smem + frag * 16) = w;
  }

  ushort_t* hsg = hseq + (size_t)gid * (CHUNK + 1) * 16 * NH;  // this group's h chain
  uint_t* flg = flags + gid * 64 * 32;                          // this group's flag row

  // c-state + h(t=-1)=0: lane owns (b = gid*16 + fq*4 + r, u = fr)
  float cc[4];
#pragma unroll
  for (int r = 0; r < 4; ++r) {
    int bg = gid * 16 + fq * 4 + r;
    if (t0 == 0) {
      cc[r] = 0.f;
      if (!(fr & 1)) {
        uint_t* p = (uint_t*)(hsg + (size_t)(fq * 4 + r) * NH + wg * 16 + fr);
        __hip_atomic_store(p, 0u, __ATOMIC_RELAXED, __HIP_MEMORY_SCOPE_AGENT);
      }
    } else {
      cc[r] = cbuf[(size_t)bg * NH + wg * 16 + fr];
    }
  }

  ushort_t gxr[16];
  auto prefetch = [&](int tl) {
    const ushort_t* src = gxc + (((size_t)tl * 64 + wg) << 12);  // [b 64][n 64] slice
#pragma unroll
    for (int nt = 0; nt < 4; ++nt)
#pragma unroll
      for (int r = 0; r < 4; ++r)
        gxr[nt * 4 + r] = src[((gid * 16 + fq * 4 + r) << 6) + nt * 16 + fr];
  };
  auto poll = [&](uint_t t) {  // whole wave polls: lane l <-> WG l
    for (;;) {
      uint_t v = __hip_atomic_load(flg + lane * 32, __ATOMIC_RELAXED, __HIP_MEMORY_SCOPE_AGENT);
      if (__all(v >= t)) break;
      __builtin_amdgcn_s_sleep(1);
    }
  };

  // init barrier (per group): weights staged (WG-wide), slot0 h + c ready
  asm volatile("s_waitcnt vmcnt(0)" ::: "memory");
  __syncthreads();  // weights visible to all waves (only syncthreads, outside loop)
  if (lane == 0)
    __hip_atomic_store(flg + wg * 32, tbase + 1, __ATOMIC_RELAXED, __HIP_MEMORY_SCOPE_AGENT);
  prefetch(0);
  poll(tbase + 1);
  __builtin_amdgcn_fence(__ATOMIC_ACQUIRE, "agent");  // drop stale hseq lines (chunk boundary)
  asm volatile("" ::: "memory");

  for (int tl = 0; tl < CHUNK; ++tl) {
    const ushort_t* hc = hsg + (size_t)tl * 16 * NH;
    // bulk-stage full-K A-fragments: 32 x 16B loads all in flight
    bf16x8 areg[32];
#pragma unroll
    for (int ks = 0; ks < 32; ++ks) {
      int ksg = (ks + wg) & 31;  // per-WG rotation de-bursts LLC lines
      areg[ks] = *(const bf16x8*)(hc + fr * NH + ksg * 32 + fq * 8);
    }
    __builtin_amdgcn_sched_barrier(0);

    f32x4 acc[4] = {zero, zero, zero, zero};
#pragma unroll
    for (int ks = 0; ks < 32; ++ks) {
      int ksg = (ks + wg) & 31;
#pragma unroll
      for (int nt = 0; nt < 4; ++nt) {
        bf16x8 w = *(const bf16x8*)(smem + ((ksg * 4 + nt) << 10) + lane16);
        acc[nt] = __builtin_amdgcn_mfma_f32_16x16x32_bf16(areg[ks], w, acc[nt], 0, 0, 0);
      }
    }

    // gates fully in-register: lane holds all 4 gate preacts of unit fr for
    // batches gid*16 + fq*4 + r  (acc row = batch, col = unit, nt = gate)
    uint_t hp[4];
#pragma unroll
    for (int r = 0; r < 4; ++r) {
      float xi = acc[0][r] + bf2f(gxr[r]);
      float xf = acc[1][r] + bf2f(gxr[4 + r]);
      float xg = acc[2][r] + bf2f(gxr[8 + r]);
      float xo = acc[3][r] + bf2f(gxr[12 + r]);
      float ig = 1.f / (1.f + __expf(-xi));
      float fg = 1.f / (1.f + __expf(-xf));
      float gg = tanh_f(xg);
      float og = 1.f / (1.f + __expf(-xo));
      cc[r] = fg * cc[r] + ig * gg;
      float hv = og * tanh_f(cc[r]);
      uint_t hb = (uint_t)f2bf(hv);
      uint_t other = (uint_t)__shfl_xor((int)hb, 1, 64);  // pair units fr<->fr^1
      hp[r] = hb | (other << 16);                          // valid on even fr
      if (!(fr & 1)) {
        int bl = fq * 4 + r;
        uint_t* hdst = (uint_t*)(hsg + (size_t)(tl + 1) * 16 * NH + (size_t)bl * NH + wg * 16 + fr);
        __hip_atomic_store(hdst, hp[r], __ATOMIC_RELAXED, __HIP_MEMORY_SCOPE_AGENT);
        if (tl == CHUNK - 1) {  // hand h(final) to next chunk's slot 0
          uint_t* h0 = (uint_t*)(hsg + (size_t)bl * NH + wg * 16 + fr);
          __hip_atomic_store(h0, hp[r], __ATOMIC_RELAXED, __HIP_MEMORY_SCOPE_AGENT);
        }
      }
    }

    // release: this wave's h-stores acked at LLC (wave-local vmcnt), then flag
    asm volatile("s_waitcnt vmcnt(0)" ::: "memory");
    uint_t t = tbase + 2 + tl;
    if (lane == 0)
      __hip_atomic_store(flg + wg * 32, t, __ATOMIC_RELAXED, __HIP_MEMORY_SCOPE_AGENT);
    // off-critical-path while the flag propagates:
    if (!(fr & 1)) {
#pragma unroll
      for (int r = 0; r < 4; ++r)
        *(uint_t*)(hs + ((size_t)(gid * 16 + fq * 4 + r) * NTT + t0 + tl) * NH + wg * 16 + fr) = hp[r];
    }
    if (tl + 1 < CHUNK) prefetch(tl + 1);
    poll(t);
    asm volatile("" ::: "memory");
  }
  // persist c for next chunk
#pragma unroll
  for (int r = 0; r < 4; ++r)
    cbuf[(size_t)(gid * 16 + fq * 4 + r) * NH + wg * 16 + fr] = cc[r];
}

// ---------------- host ----------------
extern "C" void kernel_launch(void* const* d_in, const int* in_sizes, int n_in,
                              void* d_out, int out_size, void* d_ws, size_t ws_size,
                              hipStream_t stream) {
  const float* x = (const float*)d_in[0];
  const float* w1 = (const float*)d_in[1];
  const float* b1 = (const float*)d_in[2];
  const float* w_ih = (const float*)d_in[3];
  const float* w_hh = (const float*)d_in[4];
  const float* b_ih = (const float*)d_in[5];
  const float* b_hh = (const float*)d_in[6];
  const float* w3 = (const float*)d_in[7];
  const float* b3 = (const float*)d_in[8];

  char* ws = (char*)d_ws;
  size_t off = 0;
  auto alloc = [&](size_t bytes) {
    char* p = ws + off;
    off += (bytes + 255) & ~(size_t)255;
    return p;
  };
  ushort_t* w1b = (ushort_t*)alloc(sizeof(ushort_t) * NH * NI);
  ushort_t* wihb = (ushort_t*)alloc(sizeof(ushort_t) * NG * NH);
  ushort_t* whhb = (ushort_t*)alloc(sizeof(ushort_t) * NG * NH);
  ushort_t* w3b = (ushort_t*)alloc(sizeof(ushort_t) * NA * NH);
  ushort_t* fb = (ushort_t*)alloc(sizeof(ushort_t) * (size_t)NB * NTT * NH);  // f, then hs (in-place)
  float* cbuf = (float*)alloc(sizeof(float) * NB * NH);
  uint_t* flags = (uint_t*)alloc(sizeof(uint_t) * 4 * 64 * 32);
  if (off > ws_size) {
    hipMemsetAsync(d_out, 0xFF, 256, stream);  // NaN sentinel: ws too small
    return;
  }

  // scratch carved out of d_out (dead before fc3 writes d_out):
  ushort_t* xb = (ushort_t*)d_out;                           // bf16 x for fc1
  ushort_t* hseq = (ushort_t*)d_out;                         // [4][CHUNK+1][16][NH] = 8.5MB (reuses xb)
  ushort_t* gxc = (ushort_t*)d_out + (size_t)NB * NTT * NI;  // [CHUNK][64][NB][64]

  auto cast = [&](const float* src, ushort_t* dst, int n) {
    cast_f32_bf16<<<dim3((n / 4 + 255) / 256), dim3(256), 0, stream>>>(src, dst, n);
  };
  cast(x, xb, NB * NTT * NI);
  cast(w1, w1b, NH * NI);
  cast(w_ih, wihb, NG * NH);
  cast(w_hh, whhb, NG * NH);
  cast(w3, w3b, NA * NH);

  // fc1 + tanh -> f (bf16)
  gemm_nt<1><<<dim3(NH / 128, NB * NTT / 128), dim3(256), 0, stream>>>(
      (const short*)xb, (const short*)w1b, b1, nullptr, fb, NB * NTT, NH, NI, 0);

  hipMemsetAsync(flags, 0, sizeof(uint_t) * 4 * 64 * 32, stream);
  int ldsz = 64 * NH * 2;  // 128 KB weights only
  hipFuncSetAttribute(reinterpret_cast<const void*>(&lstm_scan),
                      hipFuncAttributeMaxDynamicSharedMemorySize, ldsz);

  for (int chunk = 0; chunk < NTT / CHUNK; ++chunk) {
    int t0 = chunk * CHUNK;
    gemm_nt<2><<<dim3(NG / 128, NB * CHUNK / 128), dim3(256), 0, stream>>>(
        (const short*)fb, (const short*)wihb, b_ih, b_hh, gxc, NB * CHUNK, NG, NH, t0);
    lstm_scan<<<dim3(64), dim3(256), ldsz, stream>>>(
        whhb, gxc, hseq, cbuf, fb, flags, t0, (uint_t)(chunk * (CHUNK + 1)));
  }

  // fc3 head -> d_out (fp32)
  gemm_nt<0><<<dim3(NA / 128, NB * NTT / 128), dim3(256), 0, stream>>>(
      (const short*)fb, (const short*)w3b, b3, nullptr, d_out, NB * NTT, NA, NH, 0);
}